// Round 9
// baseline (369.452 us; speedup 1.0000x reference)
//
#include <hip/hip_runtime.h>
#include <math.h>

using u16 = unsigned short;
typedef __bf16 bf16x8 __attribute__((ext_vector_type(8)));
typedef float f32x4 __attribute__((ext_vector_type(4)));

#define BB 4
#define NN 4096
#define DD 256
#define DD2 512
#define CC2 1024
static constexpr int ROWS = BB * NN;  // 16384
static constexpr size_t MB = 1024 * 1024;

__device__ __forceinline__ u16 f2bf(float f) {
  union { float f; unsigned u; } v; v.f = f;
  unsigned r = v.u + 0x7fffu + ((v.u >> 16) & 1u);
  return (u16)(r >> 16);
}
__device__ __forceinline__ float bf2f(u16 u) {
  union { unsigned u; float f; } v; v.u = ((unsigned)u) << 16;
  return v.f;
}
__device__ __forceinline__ float u2f(unsigned x) {
  union { unsigned u; float f; } v; v.u = x; return v.f;
}

// ---------------- one-shot weight prep: all transposes/casts in ONE launch ----------------
__global__ __launch_bounds__(256) void wprep_all(
    const float* __restrict__ w_x1, const float* __restrict__ w_rep,
    const float* __restrict__ w_fc1, const float* __restrict__ w_fc2,
    const float* __restrict__ w_cat, const float* __restrict__ w_exp,
    const float* __restrict__ w_dw,
    u16* __restrict__ w_x1t, u16* __restrict__ w_rept,
    u16* __restrict__ w_fc1t, u16* __restrict__ w_fc2t,
    u16* __restrict__ w_catt, u16* __restrict__ w_expt,
    float* __restrict__ w_dwt) {
  int i = blockIdx.x * 256 + threadIdx.x;
  if (i < 65536) { int n = i >> 8, k = i & 255; w_x1t[i] = f2bf(w_x1[k * 256 + n]); return; }
  i -= 65536;
  if (i < 131072) { int n = i >> 8, k = i & 255; w_rept[i] = f2bf(w_rep[k * 512 + n]); return; }
  i -= 131072;
  if (i < 524288) { int n = i >> 9, k = i & 511; w_fc1t[i] = f2bf(w_fc1[k * 1024 + n]); return; }
  i -= 524288;
  if (i < 524288) { int n = i >> 10, k = i & 1023; w_fc2t[i] = f2bf(w_fc2[k * 512 + n]); return; }
  i -= 524288;
  if (i < 131072) { int n = i >> 9, k = i & 511; w_catt[i] = f2bf(w_cat[k * 256 + n]); return; }
  i -= 131072;
  if (i < 262144) { int n = i >> 8, k = i & 255; w_expt[i] = f2bf(w_exp[k * 1024 + n]); return; }
  i -= 262144;
  if (i < 27648) { int widx = i >> 10, c = i & 1023; w_dwt[i] = w_dw[c * 27 + widx]; }
}

// ---------------- generic 128x128-tile MFMA GEMM ----------------
// A [M][K] bf16 (or fp32 when AF32), Bt [N][K] bf16, C row-major [M][Ncols]
// EPI: 0 = f32 out, 1 = bf16 out, 2 = bf16 out + bf16 residual,
//      3 = f32 out with fused per-row LN over the 128-col tile (PatchExpand)
template <int K, int EPI, bool AF32 = false>
__global__ __launch_bounds__(256, 2) void gemm_mfma(
    const u16* __restrict__ A, const u16* __restrict__ Bt,
    const float* __restrict__ bias, const u16* __restrict__ resid,
    void* __restrict__ Cout, int nTilesN,
    const float* __restrict__ gup, const float* __restrict__ beup) {
  const int t = threadIdx.x;
  const int m0 = (blockIdx.x / nTilesN) * 128;
  const int n0 = (blockIdx.x % nTilesN) * 128;
  const int Ncols = nTilesN * 128;
  const int lane = t & 63, wid = t >> 6;
  const int wr = wid >> 1, wc = wid & 1;
  const int lrow = lane & 15, kgrp = lane >> 4;

  __shared__ u16 ldsA[2][128 * 32];
  __shared__ u16 ldsB[2][128 * 32];

  int srow[2], sslot[2];
#pragma unroll
  for (int c = 0; c < 2; ++c) {
    int idx = c * 256 + t;
    srow[c] = idx >> 2;
    sslot[c] = (idx & 3) ^ ((srow[c] >> 1) & 3);
  }

  int offA[4], offB[4];
#pragma unroll
  for (int m = 0; m < 4; ++m) {
    int r = wr * 64 + m * 16 + lrow;
    offA[m] = r * 32 + ((kgrp ^ ((r >> 1) & 3)) * 8);
  }
#pragma unroll
  for (int n = 0; n < 4; ++n) {
    int r = wc * 64 + n * 16 + lrow;
    offB[n] = r * 32 + ((kgrp ^ ((r >> 1) & 3)) * 8);
  }

  f32x4 acc[4][4];
#pragma unroll
  for (int m = 0; m < 4; ++m)
#pragma unroll
    for (int n = 0; n < 4; ++n) acc[m][n] = f32x4{0.f, 0.f, 0.f, 0.f};

  auto loadA = [&](int c, int kc) -> uint4 {
    if constexpr (AF32) {
      const float* A32 = (const float*)A;
      const float* p = A32 + (size_t)(m0 + srow[c]) * K + kc + sslot[c] * 8;
      float4 f0 = *(const float4*)p;
      float4 f1 = *(const float4*)(p + 4);
      u16 o[8] = {f2bf(f0.x), f2bf(f0.y), f2bf(f0.z), f2bf(f0.w),
                  f2bf(f1.x), f2bf(f1.y), f2bf(f1.z), f2bf(f1.w)};
      return *(uint4*)o;
    } else {
      return *(const uint4*)(A + (size_t)(m0 + srow[c]) * K + kc + sslot[c] * 8);
    }
  };

  uint4 ra[2], rb[2];
#pragma unroll
  for (int c = 0; c < 2; ++c) {
    ra[c] = loadA(c, 0);
    rb[c] = *(const uint4*)(Bt + (size_t)(n0 + srow[c]) * K + sslot[c] * 8);
  }
#pragma unroll
  for (int c = 0; c < 2; ++c) {
    int idx = c * 256 + t;
    *(uint4*)&ldsA[0][idx * 8] = ra[c];
    *(uint4*)&ldsB[0][idx * 8] = rb[c];
  }
  __syncthreads();

  const int nt = K / 32;
  for (int tt = 0; tt < nt; ++tt) {
    const int cur = tt & 1;
    if (tt + 1 < nt) {
      const int kc = (tt + 1) * 32;
#pragma unroll
      for (int c = 0; c < 2; ++c) {
        ra[c] = loadA(c, kc);
        rb[c] = *(const uint4*)(Bt + (size_t)(n0 + srow[c]) * K + kc + sslot[c] * 8);
      }
    }
    bf16x8 af[4], bf[4];
#pragma unroll
    for (int m = 0; m < 4; ++m) af[m] = *(const bf16x8*)&ldsA[cur][offA[m]];
#pragma unroll
    for (int n = 0; n < 4; ++n) bf[n] = *(const bf16x8*)&ldsB[cur][offB[n]];
#pragma unroll
    for (int m = 0; m < 4; ++m)
#pragma unroll
      for (int n = 0; n < 4; ++n)
        acc[m][n] = __builtin_amdgcn_mfma_f32_16x16x32_bf16(af[m], bf[n], acc[m][n], 0, 0, 0);
    if (tt + 1 < nt) {
#pragma unroll
      for (int c = 0; c < 2; ++c) {
        int idx = c * 256 + t;
        *(uint4*)&ldsA[cur ^ 1][idx * 8] = ra[c];
        *(uint4*)&ldsB[cur ^ 1][idx * 8] = rb[c];
      }
    }
    __syncthreads();
  }

  if (EPI == 3) {
    __shared__ float lnS[2][128], lnQ[2][128];
    float s_[4][4], q_[4][4];
#pragma unroll
    for (int m = 0; m < 4; ++m)
#pragma unroll
      for (int j = 0; j < 4; ++j) {
        float s = 0.f, q = 0.f;
#pragma unroll
        for (int n = 0; n < 4; ++n) {
          float v = acc[m][n][j];
          s += v; q += v * v;
        }
        s_[m][j] = s; q_[m][j] = q;
      }
#pragma unroll
    for (int msk = 1; msk < 16; msk <<= 1) {
#pragma unroll
      for (int m = 0; m < 4; ++m)
#pragma unroll
        for (int j = 0; j < 4; ++j) {
          s_[m][j] += __shfl_xor(s_[m][j], msk, 64);
          q_[m][j] += __shfl_xor(q_[m][j], msk, 64);
        }
    }
    if (lrow == 0) {
#pragma unroll
      for (int m = 0; m < 4; ++m)
#pragma unroll
        for (int j = 0; j < 4; ++j) {
          int r = wr * 64 + m * 16 + kgrp * 4 + j;
          lnS[wc][r] = s_[m][j];
          lnQ[wc][r] = q_[m][j];
        }
    }
    __syncthreads();
#pragma unroll
    for (int m = 0; m < 4; ++m) {
      const int rb0 = wr * 64 + m * 16 + kgrp * 4;
#pragma unroll
      for (int j = 0; j < 4; ++j) {
        const int r = rb0 + j;
        float S = lnS[0][r] + lnS[1][r];
        float Q = lnQ[0][r] + lnQ[1][r];
        float mean = S * (1.0f / 128.0f);
        float var = Q * (1.0f / 128.0f) - mean * mean;
        float iv = rsqrtf(var + 1e-5f);
#pragma unroll
        for (int n = 0; n < 4; ++n) {
          int lc = wc * 64 + n * 16 + lrow;
          ((float*)Cout)[(size_t)(m0 + r) * Ncols + n0 + lc] =
              (acc[m][n][j] - mean) * iv * gup[lc] + beup[lc];
        }
      }
    }
    return;
  }

  float bcol[4];
#pragma unroll
  for (int n = 0; n < 4; ++n) {
    int col = n0 + wc * 64 + n * 16 + (lane & 15);
    bcol[n] = bias ? bias[col] : 0.f;
  }
#pragma unroll
  for (int m = 0; m < 4; ++m) {
    const int r0 = m0 + wr * 64 + m * 16 + kgrp * 4;
#pragma unroll
    for (int n = 0; n < 4; ++n) {
      const int col = n0 + wc * 64 + n * 16 + (lane & 15);
#pragma unroll
      for (int j = 0; j < 4; ++j) {
        float v = acc[m][n][j] + bcol[n];
        size_t idx = (size_t)(r0 + j) * Ncols + col;
        if (EPI == 0) {
          ((float*)Cout)[idx] = v;
        } else if (EPI == 1) {
          ((u16*)Cout)[idx] = f2bf(v);
        } else {
          v += bf2f(resid[idx]);
          ((u16*)Cout)[idx] = f2bf(v);
        }
      }
    }
  }
}

// ------- LN over 256 cols; bf16 or fp32 input; optional row-out / transposed-out -------
template <bool INBF, bool ROWOUT, bool TOUT>
__global__ __launch_bounds__(256) void ln256x(const void* __restrict__ in,
                                              const float* __restrict__ g,
                                              const float* __restrict__ be,
                                              u16* __restrict__ rowout,
                                              u16* __restrict__ tout) {
  const int row = blockIdx.x, t = threadIdx.x;
  __shared__ float ws[8];
  float v;
  if (INBF) v = bf2f(((const u16*)in)[(size_t)row * DD + t]);
  else v = ((const float*)in)[(size_t)row * DD + t];
  float s = v, q = v * v;
#pragma unroll
  for (int m = 1; m < 64; m <<= 1) {
    s += __shfl_xor(s, m, 64);
    q += __shfl_xor(q, m, 64);
  }
  if ((t & 63) == 0) { ws[t >> 6] = s; ws[4 + (t >> 6)] = q; }
  __syncthreads();
  s = ws[0] + ws[1] + ws[2] + ws[3];
  q = ws[4] + ws[5] + ws[6] + ws[7];
  float mean = s * (1.0f / DD);
  float var = q * (1.0f / DD) - mean * mean;
  float iv = rsqrtf(var + 1e-5f);
  u16 rb = f2bf((v - mean) * iv * g[t] + be[t]);
  if (ROWOUT) rowout[(size_t)row * DD + t] = rb;
  if (TOUT) {
    int b = row >> 12, n = row & 4095;
    tout[((size_t)(b * 256 + t)) * 4096 + n] = rb;
  }
}

// ------- k34: fused column-softmax stats + ctx, coalesced via n2T/n1T -------
__global__ __launch_bounds__(256) void k34_ctx(
    const u16* __restrict__ n2T, const u16* __restrict__ n1T,
    float* __restrict__ ctx) {
  const int bid = blockIdx.x;
  const int bx = (bid & 7) * 128 + (bid >> 3);  // bijective, 1024%8==0
  const int b = bx >> 8, d = bx & 255;
  const int h = d >> 5, kk = d & 31;
  const int t = threadIdx.x;
  __shared__ u16 prow[4096];
  __shared__ float xred[8];
  __shared__ float sw[128];
  const u16* src = n2T + (size_t)bx * 4096;
  ((uint4*)prow)[t] = ((const uint4*)src)[t];
  ((uint4*)prow)[256 + t] = ((const uint4*)src)[256 + t];
  __syncthreads();
  float mx = -1e30f;
#pragma unroll
  for (int i = 0; i < 16; ++i) mx = fmaxf(mx, bf2f(prow[i * 256 + t]));
#pragma unroll
  for (int m = 1; m < 64; m <<= 1) mx = fmaxf(mx, __shfl_xor(mx, m, 64));
  if ((t & 63) == 0) xred[t >> 6] = mx;
  __syncthreads();
  mx = fmaxf(fmaxf(xred[0], xred[1]), fmaxf(xred[2], xred[3]));
  float sme = 0.f;
#pragma unroll
  for (int i = 0; i < 16; ++i) sme += __expf(bf2f(prow[i * 256 + t]) - mx);
#pragma unroll
  for (int m = 1; m < 64; m <<= 1) sme += __shfl_xor(sme, m, 64);
  if ((t & 63) == 0) xred[4 + (t >> 6)] = sme;
  __syncthreads();
  const float inv = 1.0f / (xred[4] + xred[5] + xred[6] + xred[7]);

  float acc[32];
#pragma unroll
  for (int v = 0; v < 32; ++v) acc[v] = 0.f;
  const u16* vbase = n1T + ((size_t)(b * 256 + h * 32)) * 4096;
  for (int i = 0; i < 16; ++i) {
    const int n = i * 256 + t;
    const float p = __expf(bf2f(prow[n]) - mx) * inv;
#pragma unroll
    for (int v = 0; v < 32; ++v)
      acc[v] += p * bf2f(vbase[(size_t)v * 4096 + n]);
  }
#pragma unroll
  for (int v = 0; v < 32; ++v) {
#pragma unroll
    for (int m = 1; m < 64; m <<= 1) acc[v] += __shfl_xor(acc[v], m, 64);
  }
  if ((t & 63) == 0) {
#pragma unroll
    for (int v = 0; v < 32; ++v) sw[(t >> 6) * 32 + v] = acc[v];
  }
  __syncthreads();
  if (t < 32)
    ctx[(((size_t)(b * 8 + h)) * 32 + kk) * 32 + t] =
        sw[t] + sw[32 + t] + sw[64 + t] + sw[96 + t];
}

// ---------------- k5: attT[b,n,d] = sum_k ctx * softmaxQ ----------------
__global__ __launch_bounds__(256) void k5_attT(
    const u16* __restrict__ n2, const float* __restrict__ ctx,
    u16* __restrict__ attT) {
  const int row = blockIdx.x, t = threadIdx.x;
  const int b = row >> 12;
  const int h = t >> 5, v = t & 31;
  __shared__ float nr[DD];
  __shared__ float q[DD];
  nr[t] = bf2f(n2[(size_t)row * DD + t]);
  __syncthreads();
  float mx = -1e30f;
  for (int c = 0; c < 32; ++c) mx = fmaxf(mx, nr[h * 32 + c]);
  float sm = 0.f;
  for (int c = 0; c < 32; ++c) sm += __expf(nr[h * 32 + c] - mx);
  q[t] = __expf(nr[t] - mx) / sm;
  __syncthreads();
  const float* cb = ctx + ((size_t)(b * 8 + h) * 32) * 32 + v;
  float acc = 0.f;
#pragma unroll
  for (int k = 0; k < 32; ++k) acc += cb[k * 32] * q[h * 32 + k];
  attT[(size_t)row * DD + t] = f2bf(acc);
}

// ------- l3: rep = LN(rep_b); tx = concat(x1e,x2)+rep; txln = LN(tx) (bf16 ins) -------
__global__ __launch_bounds__(256) void l3_reptx(
    const u16* __restrict__ rep_b, const u16* __restrict__ x1e,
    const float* __restrict__ x2,
    const float* __restrict__ g_an, const float* __restrict__ be_an,
    const float* __restrict__ g_n2, const float* __restrict__ be_n2,
    u16* __restrict__ tx, u16* __restrict__ txln) {
  const int row = blockIdx.x, t = threadIdx.x;
  __shared__ float ws[8];
  float a0 = bf2f(rep_b[(size_t)row * DD2 + t]);
  float a1 = bf2f(rep_b[(size_t)row * DD2 + 256 + t]);
  float s = a0 + a1, q = a0 * a0 + a1 * a1;
#pragma unroll
  for (int m = 1; m < 64; m <<= 1) {
    s += __shfl_xor(s, m, 64);
    q += __shfl_xor(q, m, 64);
  }
  if ((t & 63) == 0) { ws[t >> 6] = s; ws[4 + (t >> 6)] = q; }
  __syncthreads();
  s = ws[0] + ws[1] + ws[2] + ws[3];
  q = ws[4] + ws[5] + ws[6] + ws[7];
  float mean = s * (1.0f / DD2);
  float var = q * (1.0f / DD2) - mean * mean;
  float iv = rsqrtf(var + 1e-5f);
  float r0 = (a0 - mean) * iv * g_an[t] + be_an[t];
  float r1 = (a1 - mean) * iv * g_an[256 + t] + be_an[256 + t];
  float t0 = bf2f(x1e[(size_t)row * DD + t]) + r0;
  float t1 = x2[(size_t)row * DD + t] + r1;
  tx[(size_t)row * DD2 + t] = f2bf(t0);
  tx[(size_t)row * DD2 + 256 + t] = f2bf(t1);
  __syncthreads();
  s = t0 + t1; q = t0 * t0 + t1 * t1;
#pragma unroll
  for (int m = 1; m < 64; m <<= 1) {
    s += __shfl_xor(s, m, 64);
    q += __shfl_xor(q, m, 64);
  }
  if ((t & 63) == 0) { ws[t >> 6] = s; ws[4 + (t >> 6)] = q; }
  __syncthreads();
  s = ws[0] + ws[1] + ws[2] + ws[3];
  q = ws[4] + ws[5] + ws[6] + ws[7];
  mean = s * (1.0f / DD2);
  var = q * (1.0f / DD2) - mean * mean;
  iv = rsqrtf(var + 1e-5f);
  txln[(size_t)row * DD2 + t] = f2bf((t0 - mean) * iv * g_n2[t] + be_n2[t]);
  txln[(size_t)row * DD2 + 256 + t] = f2bf((t1 - mean) * iv * g_n2[256 + t] + be_n2[256 + t]);
}

// ------- c8a_col4: dw-conv3d + skip + LN + GELU, 4 z-slices per block -------
// 4096 blocks x 1024 threads (1 ch/thread). Serial chain per thread is 4
// iterations (vs 16): 4x wave-parallelism for latency hiding. XCD-chunked so
// each chunk's columns share their halo in L2. LN is block-local.
__global__ __launch_bounds__(1024) void c8a_col4(
    const u16* __restrict__ h, const float* __restrict__ w_dwt,
    const float* __restrict__ b_dw, const float* __restrict__ g,
    const float* __restrict__ be, u16* __restrict__ ax) {
  const int bid = blockIdx.x;
  const int chunk = bid & 7, inner = bid >> 3;      // chunk -> XCD
  const int cidx = chunk * 128 + (inner & 127);     // (b,y,x) column
  const int zg = inner >> 7;                        // z-group 0..3
  const int zbase = zg * 4;
  const int b = cidx >> 8, y = (cidx >> 4) & 15, x = cidx & 15;
  const int t = threadIdx.x;  // channel
  const int lane = t & 63, wave = t >> 6;  // 16 waves
  const size_t hb = (size_t)b * NN * CC2;

  __shared__ float2 red[4][16];
  __shared__ float2 stats[4];

  int coln[9];
  float cmask[9];
#pragma unroll
  for (int dy = -1; dy <= 1; ++dy)
#pragma unroll
    for (int dx = -1; dx <= 1; ++dx) {
      int qq = (dy + 1) * 3 + (dx + 1);
      int yy = y + dy, xx = x + dx;
      bool ok = ((unsigned)yy < 16u) && ((unsigned)xx < 16u);
      coln[qq] = ((ok ? yy : y) << 4) | (ok ? xx : x);
      cmask[qq] = ok ? 1.f : 0.f;
    }

  float wr[3][9];
#pragma unroll
  for (int p = 0; p < 3; ++p)
#pragma unroll
    for (int qq = 0; qq < 9; ++qq)
      wr[p][qq] = w_dwt[(p * 9 + qq) * CC2 + t] * cmask[qq];
  const float bias = b_dw[t];

  u16 win[3][9];
#define LOADPLANE(ZL, SLOT)                                                   \
  do {                                                                        \
    if ((ZL) >= 0 && (ZL) < 16) {                                             \
      _Pragma("unroll") for (int qq = 0; qq < 9; ++qq) win[SLOT][qq] =        \
          h[hb + (size_t)((((ZL) << 8) | coln[qq])) * CC2 + t];               \
    } else {                                                                  \
      _Pragma("unroll") for (int qq = 0; qq < 9; ++qq) win[SLOT][qq] = 0;     \
    }                                                                         \
  } while (0)

  LOADPLANE(zbase - 1, 0);
  LOADPLANE(zbase, 1);
  LOADPLANE(zbase + 1, 2);

  float vs[4];
#pragma unroll
  for (int zi = 0; zi < 4; ++zi) {
    const int pm1 = zi % 3, pz = (zi + 1) % 3, pp1 = (zi + 2) % 3;
    float a0 = bias;
#pragma unroll
    for (int qq = 0; qq < 9; ++qq) {
      a0 += bf2f(win[pm1][qq]) * wr[0][qq];
      a0 += bf2f(win[pz][qq]) * wr[1][qq];
      a0 += bf2f(win[pp1][qq]) * wr[2][qq];
    }
    float v = a0 + bf2f(win[pz][4]);  // skip-add (center)
    LOADPLANE(zbase + zi + 2, pm1);   // prefetch next plane into dead slot
    vs[zi] = v;
    float s = v, q2 = v * v;
#pragma unroll
    for (int m = 1; m < 64; m <<= 1) {
      s += __shfl_xor(s, m, 64);
      q2 += __shfl_xor(q2, m, 64);
    }
    if (lane == 0) red[zi][wave] = make_float2(s, q2);
  }
#undef LOADPLANE
  __syncthreads();

  if (wave < 4) {
    const int zi = wave;
    float S = (lane < 16) ? red[zi][lane].x : 0.f;
    float Q = (lane < 16) ? red[zi][lane].y : 0.f;
#pragma unroll
    for (int m = 1; m < 16; m <<= 1) {
      S += __shfl_xor(S, m, 64);
      Q += __shfl_xor(Q, m, 64);
    }
    if (lane == 0) {
      float mean = S * (1.0f / CC2);
      float var = Q * (1.0f / CC2) - mean * mean;
      stats[zi] = make_float2(mean, rsqrtf(var + 1e-5f));
    }
  }
  __syncthreads();

  const float gg = g[t], bb = be[t];
#pragma unroll
  for (int zi = 0; zi < 4; ++zi) {
    float2 st = stats[zi];
    float u = (vs[zi] - st.x) * st.y * gg + bb;
    float s2 = 1.5957691216f * (u + 0.044715f * u * u * u);
    float o = u / (1.0f + __expf(-s2));
    ax[((size_t)(b * NN + (((zbase + zi) << 8) | (y << 4) | x))) * CC2 + t] = f2bf(o);
  }
}

extern "C" void kernel_launch(void* const* d_in, const int* in_sizes, int n_in,
                              void* d_out, int out_size, void* d_ws, size_t ws_size,
                              hipStream_t stream) {
  const float* x1    = (const float*)d_in[0];
  const float* x2    = (const float*)d_in[1];
  const float* w_x1  = (const float*)d_in[2];
  const float* b_x1  = (const float*)d_in[3];
  const float* g_n1  = (const float*)d_in[4];
  const float* be_n1 = (const float*)d_in[5];
  const float* w_rep = (const float*)d_in[6];
  const float* b_rep = (const float*)d_in[7];
  const float* g_an  = (const float*)d_in[8];
  const float* be_an = (const float*)d_in[9];
  const float* g_n2  = (const float*)d_in[10];
  const float* be_n2 = (const float*)d_in[11];
  const float* w_fc1 = (const float*)d_in[12];
  const float* b_fc1 = (const float*)d_in[13];
  const float* w_dw  = (const float*)d_in[14];
  const float* b_dw  = (const float*)d_in[15];
  const float* g_m1  = (const float*)d_in[16];
  const float* be_m1 = (const float*)d_in[17];
  const float* w_fc2 = (const float*)d_in[18];
  const float* b_fc2 = (const float*)d_in[19];
  const float* w_cat = (const float*)d_in[20];
  const float* b_cat = (const float*)d_in[21];
  const float* w_exp = (const float*)d_in[22];
  const float* g_up  = (const float*)d_in[23];
  const float* be_up = (const float*)d_in[24];

  char* ws = (char*)d_ws;
  float* out = (float*)d_out;

  u16*   x1e_b   = (u16*)(ws + 8 * MB);     // bf16 x1e; then mx
  u16*   n1T     = (u16*)(ws + 24 * MB);
  u16*   n2b     = (u16*)(ws + 32 * MB);
  u16*   n2T     = (u16*)(ws + 40 * MB);
  float* ctx     = (float*)(ws + 48 * MB);
  u16*   rep_b   = (u16*)(ws + 49 * MB);    // bf16 rep; then ax
  u16*   tx      = (u16*)(ws + 81 * MB);
  u16*   txln    = (u16*)(ws + 97 * MB);
  u16*   hbuf    = (u16*)(ws + 113 * MB);
  u16*   attT    = (u16*)(ws + 0);
  u16*   ax      = (u16*)(ws + 49 * MB);
  u16*   mx      = (u16*)(ws + 8 * MB);
  u16*   ybuf    = (u16*)(ws + 0);
  u16*   w_x1t   = (u16*)(ws + 145 * MB);
  u16*   w_rept  = w_x1t + 256 * 256;
  u16*   w_fc1t  = w_rept + 512 * 256;
  u16*   w_fc2t  = w_fc1t + 1024 * 512;
  u16*   w_catt  = w_fc2t + 512 * 1024;
  u16*   w_expt  = w_catt + 256 * 512;
  float* w_dwt   = (float*)(ws + 149 * MB);

  wprep_all<<<(1666048 + 255) / 256, 256, 0, stream>>>(
      w_x1, w_rep, w_fc1, w_fc2, w_cat, w_exp, w_dw,
      w_x1t, w_rept, w_fc1t, w_fc2t, w_catt, w_expt, w_dwt);

  gemm_mfma<256, 1, true><<<(ROWS / 128) * 2, 256, 0, stream>>>(
      (const u16*)x1, w_x1t, b_x1, nullptr, x1e_b, 2, nullptr, nullptr);
  ln256x<true, false, true><<<ROWS, 256, 0, stream>>>(x1e_b, g_n1, be_n1, nullptr, n1T);
  ln256x<false, true, true><<<ROWS, 256, 0, stream>>>(x2, g_n1, be_n1, n2b, n2T);
  k34_ctx<<<BB * 256, 256, 0, stream>>>(n2T, n1T, ctx);
  k5_attT<<<ROWS, 256, 0, stream>>>(n2b, ctx, attT);
  gemm_mfma<256, 1><<<(ROWS / 128) * 4, 256, 0, stream>>>(
      attT, w_rept, b_rep, nullptr, rep_b, 4, nullptr, nullptr);
  l3_reptx<<<ROWS, 256, 0, stream>>>(rep_b, x1e_b, x2, g_an, be_an, g_n2, be_n2, tx, txln);
  gemm_mfma<512, 1><<<(ROWS / 128) * 8, 256, 0, stream>>>(
      txln, w_fc1t, b_fc1, nullptr, hbuf, 8, nullptr, nullptr);
  c8a_col4<<<4096, 1024, 0, stream>>>(hbuf, w_dwt, b_dw, g_m1, be_m1, ax);
  gemm_mfma<1024, 2><<<(ROWS / 128) * 4, 256, 0, stream>>>(
      ax, w_fc2t, b_fc2, tx, mx, 4, nullptr, nullptr);
  gemm_mfma<512, 1><<<(ROWS / 128) * 2, 256, 0, stream>>>(
      mx, w_catt, b_cat, nullptr, ybuf, 2, nullptr, nullptr);
  gemm_mfma<256, 3><<<(ROWS / 128) * 8, 256, 0, stream>>>(
      ybuf, w_expt, nullptr, nullptr, out, 8, g_up, be_up);
}

// Round 10
// 320.332 us; speedup vs baseline: 1.1533x; 1.1533x over previous
//
#include <hip/hip_runtime.h>
#include <math.h>

using u16 = unsigned short;
typedef __bf16 bf16x8 __attribute__((ext_vector_type(8)));
typedef float f32x4 __attribute__((ext_vector_type(4)));

#define BB 4
#define NN 4096
#define DD 256
#define DD2 512
#define CC2 1024
static constexpr int ROWS = BB * NN;  // 16384
static constexpr size_t MB = 1024 * 1024;

__device__ __forceinline__ u16 f2bf(float f) {
  union { float f; unsigned u; } v; v.f = f;
  unsigned r = v.u + 0x7fffu + ((v.u >> 16) & 1u);
  return (u16)(r >> 16);
}
__device__ __forceinline__ float bf2f(u16 u) {
  union { unsigned u; float f; } v; v.u = ((unsigned)u) << 16;
  return v.f;
}
__device__ __forceinline__ float u2f(unsigned x) {
  union { unsigned u; float f; } v; v.u = x; return v.f;
}
// async 16B global->LDS (wave-uniform LDS base + lane*16; global src per-lane)
__device__ __forceinline__ void gload16(const void* g, void* l) {
  __builtin_amdgcn_global_load_lds(
      (const __attribute__((address_space(1))) void*)g,
      (__attribute__((address_space(3))) void*)l, 16, 0, 0);
}

// ---------------- one-shot weight prep: all transposes/casts in ONE launch ----------------
__global__ __launch_bounds__(256) void wprep_all(
    const float* __restrict__ w_x1, const float* __restrict__ w_rep,
    const float* __restrict__ w_fc1, const float* __restrict__ w_fc2,
    const float* __restrict__ w_cat, const float* __restrict__ w_exp,
    const float* __restrict__ w_dw,
    u16* __restrict__ w_x1t, u16* __restrict__ w_rept,
    u16* __restrict__ w_fc1t, u16* __restrict__ w_fc2t,
    u16* __restrict__ w_catt, u16* __restrict__ w_expt,
    float* __restrict__ w_dwt) {
  int i = blockIdx.x * 256 + threadIdx.x;
  if (i < 65536) { int n = i >> 8, k = i & 255; w_x1t[i] = f2bf(w_x1[k * 256 + n]); return; }
  i -= 65536;
  if (i < 131072) { int n = i >> 8, k = i & 255; w_rept[i] = f2bf(w_rep[k * 512 + n]); return; }
  i -= 131072;
  if (i < 524288) { int n = i >> 9, k = i & 511; w_fc1t[i] = f2bf(w_fc1[k * 1024 + n]); return; }
  i -= 524288;
  if (i < 524288) { int n = i >> 10, k = i & 1023; w_fc2t[i] = f2bf(w_fc2[k * 512 + n]); return; }
  i -= 524288;
  if (i < 131072) { int n = i >> 9, k = i & 511; w_catt[i] = f2bf(w_cat[k * 256 + n]); return; }
  i -= 131072;
  if (i < 262144) { int n = i >> 8, k = i & 255; w_expt[i] = f2bf(w_exp[k * 1024 + n]); return; }
  i -= 262144;
  if (i < 27648) { int widx = i >> 10, c = i & 1023; w_dwt[i] = w_dw[c * 27 + widx]; }
}

// ---------------- generic 128x128-tile MFMA GEMM ----------------
// A [M][K] bf16 (or fp32 when AF32), Bt [N][K] bf16, C row-major [M][Ncols]
// Staging: bf16-A path uses async global_load_lds width=16 (linear LDS dest;
// XOR permutation applied on the GLOBAL source -> conflict-free ds_read_b128).
// EPI: 0 = f32 out, 1 = bf16 out, 2 = bf16 out + bf16 residual,
//      3 = f32 out with fused per-row LN over the 128-col tile (PatchExpand)
template <int K, int EPI, bool AF32 = false>
__global__ __launch_bounds__(256, 2) void gemm_mfma(
    const u16* __restrict__ A, const u16* __restrict__ Bt,
    const float* __restrict__ bias, const u16* __restrict__ resid,
    void* __restrict__ Cout, int nTilesN,
    const float* __restrict__ gup, const float* __restrict__ beup) {
  const int t = threadIdx.x;
  const int m0 = (blockIdx.x / nTilesN) * 128;
  const int n0 = (blockIdx.x % nTilesN) * 128;
  const int Ncols = nTilesN * 128;
  const int lane = t & 63, wid = t >> 6;
  const int wr = wid >> 1, wc = wid & 1;
  const int lrow = lane & 15, kgrp = lane >> 4;

  __shared__ u16 ldsA[2][128 * 32];
  __shared__ u16 ldsB[2][128 * 32];

  int srow[2], sslot[2];
#pragma unroll
  for (int c = 0; c < 2; ++c) {
    int idx = c * 256 + t;
    srow[c] = idx >> 2;
    sslot[c] = (idx & 3) ^ ((srow[c] >> 1) & 3);
  }

  int offA[4], offB[4];
#pragma unroll
  for (int m = 0; m < 4; ++m) {
    int r = wr * 64 + m * 16 + lrow;
    offA[m] = r * 32 + ((kgrp ^ ((r >> 1) & 3)) * 8);
  }
#pragma unroll
  for (int n = 0; n < 4; ++n) {
    int r = wc * 64 + n * 16 + lrow;
    offB[n] = r * 32 + ((kgrp ^ ((r >> 1) & 3)) * 8);
  }

  f32x4 acc[4][4];
#pragma unroll
  for (int m = 0; m < 4; ++m)
#pragma unroll
    for (int n = 0; n < 4; ++n) acc[m][n] = f32x4{0.f, 0.f, 0.f, 0.f};

  auto loadA32 = [&](int c, int kc) -> uint4 {
    const float* A32 = (const float*)A;
    const float* p = A32 + (size_t)(m0 + srow[c]) * K + kc + sslot[c] * 8;
    float4 f0 = *(const float4*)p;
    float4 f1 = *(const float4*)(p + 4);
    u16 o[8] = {f2bf(f0.x), f2bf(f0.y), f2bf(f0.z), f2bf(f0.w),
                f2bf(f1.x), f2bf(f1.y), f2bf(f1.z), f2bf(f1.w)};
    return *(uint4*)o;
  };
  auto stage_async = [&](int buf, int kc) {
#pragma unroll
    for (int c = 0; c < 2; ++c) {
      gload16(A + (size_t)(m0 + srow[c]) * K + kc + sslot[c] * 8,
              &ldsA[buf][(c * 256 + t) * 8]);
      gload16(Bt + (size_t)(n0 + srow[c]) * K + kc + sslot[c] * 8,
              &ldsB[buf][(c * 256 + t) * 8]);
    }
  };

  uint4 ra[2], rb[2];
  if constexpr (AF32) {
#pragma unroll
    for (int c = 0; c < 2; ++c) {
      ra[c] = loadA32(c, 0);
      rb[c] = *(const uint4*)(Bt + (size_t)(n0 + srow[c]) * K + sslot[c] * 8);
    }
#pragma unroll
    for (int c = 0; c < 2; ++c) {
      int idx = c * 256 + t;
      *(uint4*)&ldsA[0][idx * 8] = ra[c];
      *(uint4*)&ldsB[0][idx * 8] = rb[c];
    }
  } else {
    stage_async(0, 0);
  }
  __syncthreads();

  const int nt = K / 32;
  for (int tt = 0; tt < nt; ++tt) {
    const int cur = tt & 1;
    if (tt + 1 < nt) {
      const int kc = (tt + 1) * 32;
      if constexpr (AF32) {
#pragma unroll
        for (int c = 0; c < 2; ++c) {
          ra[c] = loadA32(c, kc);
          rb[c] = *(const uint4*)(Bt + (size_t)(n0 + srow[c]) * K + kc + sslot[c] * 8);
        }
      } else {
        stage_async(cur ^ 1, kc);
      }
    }
    bf16x8 af[4], bf[4];
#pragma unroll
    for (int m = 0; m < 4; ++m) af[m] = *(const bf16x8*)&ldsA[cur][offA[m]];
#pragma unroll
    for (int n = 0; n < 4; ++n) bf[n] = *(const bf16x8*)&ldsB[cur][offB[n]];
#pragma unroll
    for (int m = 0; m < 4; ++m)
#pragma unroll
      for (int n = 0; n < 4; ++n)
        acc[m][n] = __builtin_amdgcn_mfma_f32_16x16x32_bf16(af[m], bf[n], acc[m][n], 0, 0, 0);
    if (AF32 && tt + 1 < nt) {
#pragma unroll
      for (int c = 0; c < 2; ++c) {
        int idx = c * 256 + t;
        *(uint4*)&ldsA[cur ^ 1][idx * 8] = ra[c];
        *(uint4*)&ldsB[cur ^ 1][idx * 8] = rb[c];
      }
    }
    __syncthreads();  // drains vmcnt(0): async stage of cur^1 complete
  }

  if (EPI == 3) {
    __shared__ float lnS[2][128], lnQ[2][128];
    float s_[4][4], q_[4][4];
#pragma unroll
    for (int m = 0; m < 4; ++m)
#pragma unroll
      for (int j = 0; j < 4; ++j) {
        float s = 0.f, q = 0.f;
#pragma unroll
        for (int n = 0; n < 4; ++n) {
          float v = acc[m][n][j];
          s += v; q += v * v;
        }
        s_[m][j] = s; q_[m][j] = q;
      }
#pragma unroll
    for (int msk = 1; msk < 16; msk <<= 1) {
#pragma unroll
      for (int m = 0; m < 4; ++m)
#pragma unroll
        for (int j = 0; j < 4; ++j) {
          s_[m][j] += __shfl_xor(s_[m][j], msk, 64);
          q_[m][j] += __shfl_xor(q_[m][j], msk, 64);
        }
    }
    if (lrow == 0) {
#pragma unroll
      for (int m = 0; m < 4; ++m)
#pragma unroll
        for (int j = 0; j < 4; ++j) {
          int r = wr * 64 + m * 16 + kgrp * 4 + j;
          lnS[wc][r] = s_[m][j];
          lnQ[wc][r] = q_[m][j];
        }
    }
    __syncthreads();
#pragma unroll
    for (int m = 0; m < 4; ++m) {
      const int rb0 = wr * 64 + m * 16 + kgrp * 4;
#pragma unroll
      for (int j = 0; j < 4; ++j) {
        const int r = rb0 + j;
        float S = lnS[0][r] + lnS[1][r];
        float Q = lnQ[0][r] + lnQ[1][r];
        float mean = S * (1.0f / 128.0f);
        float var = Q * (1.0f / 128.0f) - mean * mean;
        float iv = rsqrtf(var + 1e-5f);
#pragma unroll
        for (int n = 0; n < 4; ++n) {
          int lc = wc * 64 + n * 16 + lrow;
          ((float*)Cout)[(size_t)(m0 + r) * Ncols + n0 + lc] =
              (acc[m][n][j] - mean) * iv * gup[lc] + beup[lc];
        }
      }
    }
    return;
  }

  float bcol[4];
#pragma unroll
  for (int n = 0; n < 4; ++n) {
    int col = n0 + wc * 64 + n * 16 + (lane & 15);
    bcol[n] = bias ? bias[col] : 0.f;
  }
#pragma unroll
  for (int m = 0; m < 4; ++m) {
    const int r0 = m0 + wr * 64 + m * 16 + kgrp * 4;
#pragma unroll
    for (int n = 0; n < 4; ++n) {
      const int col = n0 + wc * 64 + n * 16 + (lane & 15);
#pragma unroll
      for (int j = 0; j < 4; ++j) {
        float v = acc[m][n][j] + bcol[n];
        size_t idx = (size_t)(r0 + j) * Ncols + col;
        if (EPI == 0) {
          ((float*)Cout)[idx] = v;
        } else if (EPI == 1) {
          ((u16*)Cout)[idx] = f2bf(v);
        } else {
          v += bf2f(resid[idx]);
          ((u16*)Cout)[idx] = f2bf(v);
        }
      }
    }
  }
}

// ------- ln256_both: one launch for both LN streams -------
// blocks [0,ROWS): n1T = LN(x1e_b) transposed-out only
// blocks [ROWS,2*ROWS): n2 = LN(x2) -> n2b row-out + n2T transposed-out
__global__ __launch_bounds__(256) void ln256_both(
    const u16* __restrict__ x1e_b, const float* __restrict__ x2,
    const float* __restrict__ g, const float* __restrict__ be,
    u16* __restrict__ n1T, u16* __restrict__ n2b, u16* __restrict__ n2T) {
  int row = blockIdx.x;
  const int t = threadIdx.x;
  const bool first = row < ROWS;
  if (!first) row -= ROWS;
  __shared__ float ws[8];
  float v = first ? bf2f(x1e_b[(size_t)row * DD + t])
                  : x2[(size_t)row * DD + t];
  float s = v, q = v * v;
#pragma unroll
  for (int m = 1; m < 64; m <<= 1) {
    s += __shfl_xor(s, m, 64);
    q += __shfl_xor(q, m, 64);
  }
  if ((t & 63) == 0) { ws[t >> 6] = s; ws[4 + (t >> 6)] = q; }
  __syncthreads();
  s = ws[0] + ws[1] + ws[2] + ws[3];
  q = ws[4] + ws[5] + ws[6] + ws[7];
  float mean = s * (1.0f / DD);
  float var = q * (1.0f / DD) - mean * mean;
  float iv = rsqrtf(var + 1e-5f);
  u16 rb = f2bf((v - mean) * iv * g[t] + be[t]);
  int b = row >> 12, n = row & 4095;
  if (first) {
    n1T[((size_t)(b * 256 + t)) * 4096 + n] = rb;
  } else {
    n2b[(size_t)row * DD + t] = rb;
    n2T[((size_t)(b * 256 + t)) * 4096 + n] = rb;
  }
}

// ------- k34: fused column-softmax stats + ctx, coalesced via n2T/n1T -------
__global__ __launch_bounds__(256) void k34_ctx(
    const u16* __restrict__ n2T, const u16* __restrict__ n1T,
    float* __restrict__ ctx) {
  const int bid = blockIdx.x;
  const int bx = (bid & 7) * 128 + (bid >> 3);  // bijective, 1024%8==0
  const int b = bx >> 8, d = bx & 255;
  const int h = d >> 5, kk = d & 31;
  const int t = threadIdx.x;
  __shared__ u16 prow[4096];
  __shared__ float xred[8];
  __shared__ float sw[128];
  const u16* src = n2T + (size_t)bx * 4096;
  ((uint4*)prow)[t] = ((const uint4*)src)[t];
  ((uint4*)prow)[256 + t] = ((const uint4*)src)[256 + t];
  __syncthreads();
  float mx = -1e30f;
#pragma unroll
  for (int i = 0; i < 16; ++i) mx = fmaxf(mx, bf2f(prow[i * 256 + t]));
#pragma unroll
  for (int m = 1; m < 64; m <<= 1) mx = fmaxf(mx, __shfl_xor(mx, m, 64));
  if ((t & 63) == 0) xred[t >> 6] = mx;
  __syncthreads();
  mx = fmaxf(fmaxf(xred[0], xred[1]), fmaxf(xred[2], xred[3]));
  float sme = 0.f;
#pragma unroll
  for (int i = 0; i < 16; ++i) sme += __expf(bf2f(prow[i * 256 + t]) - mx);
#pragma unroll
  for (int m = 1; m < 64; m <<= 1) sme += __shfl_xor(sme, m, 64);
  if ((t & 63) == 0) xred[4 + (t >> 6)] = sme;
  __syncthreads();
  const float inv = 1.0f / (xred[4] + xred[5] + xred[6] + xred[7]);

  float acc[32];
#pragma unroll
  for (int v = 0; v < 32; ++v) acc[v] = 0.f;
  const u16* vbase = n1T + ((size_t)(b * 256 + h * 32)) * 4096;
  for (int i = 0; i < 16; ++i) {
    const int n = i * 256 + t;
    const float p = __expf(bf2f(prow[n]) - mx) * inv;
#pragma unroll
    for (int v = 0; v < 32; ++v)
      acc[v] += p * bf2f(vbase[(size_t)v * 4096 + n]);
  }
#pragma unroll
  for (int v = 0; v < 32; ++v) {
#pragma unroll
    for (int m = 1; m < 64; m <<= 1) acc[v] += __shfl_xor(acc[v], m, 64);
  }
  if ((t & 63) == 0) {
#pragma unroll
    for (int v = 0; v < 32; ++v) sw[(t >> 6) * 32 + v] = acc[v];
  }
  __syncthreads();
  if (t < 32)
    ctx[(((size_t)(b * 8 + h)) * 32 + kk) * 32 + t] =
        sw[t] + sw[32 + t] + sw[64 + t] + sw[96 + t];
}

// ---------------- k5: attT[b,n,d] = sum_k ctx * softmaxQ ----------------
__global__ __launch_bounds__(256) void k5_attT(
    const u16* __restrict__ n2, const float* __restrict__ ctx,
    u16* __restrict__ attT) {
  const int row = blockIdx.x, t = threadIdx.x;
  const int b = row >> 12;
  const int h = t >> 5, v = t & 31;
  __shared__ float nr[DD];
  __shared__ float q[DD];
  nr[t] = bf2f(n2[(size_t)row * DD + t]);
  __syncthreads();
  float mx = -1e30f;
  for (int c = 0; c < 32; ++c) mx = fmaxf(mx, nr[h * 32 + c]);
  float sm = 0.f;
  for (int c = 0; c < 32; ++c) sm += __expf(nr[h * 32 + c] - mx);
  q[t] = __expf(nr[t] - mx) / sm;
  __syncthreads();
  const float* cb = ctx + ((size_t)(b * 8 + h) * 32) * 32 + v;
  float acc = 0.f;
#pragma unroll
  for (int k = 0; k < 32; ++k) acc += cb[k * 32] * q[h * 32 + k];
  attT[(size_t)row * DD + t] = f2bf(acc);
}

// ------- l3: rep = LN(rep_b); tx = concat(x1e,x2)+rep; txln = LN(tx) (bf16 ins) -------
__global__ __launch_bounds__(256) void l3_reptx(
    const u16* __restrict__ rep_b, const u16* __restrict__ x1e,
    const float* __restrict__ x2,
    const float* __restrict__ g_an, const float* __restrict__ be_an,
    const float* __restrict__ g_n2, const float* __restrict__ be_n2,
    u16* __restrict__ tx, u16* __restrict__ txln) {
  const int row = blockIdx.x, t = threadIdx.x;
  __shared__ float ws[8];
  float a0 = bf2f(rep_b[(size_t)row * DD2 + t]);
  float a1 = bf2f(rep_b[(size_t)row * DD2 + 256 + t]);
  float s = a0 + a1, q = a0 * a0 + a1 * a1;
#pragma unroll
  for (int m = 1; m < 64; m <<= 1) {
    s += __shfl_xor(s, m, 64);
    q += __shfl_xor(q, m, 64);
  }
  if ((t & 63) == 0) { ws[t >> 6] = s; ws[4 + (t >> 6)] = q; }
  __syncthreads();
  s = ws[0] + ws[1] + ws[2] + ws[3];
  q = ws[4] + ws[5] + ws[6] + ws[7];
  float mean = s * (1.0f / DD2);
  float var = q * (1.0f / DD2) - mean * mean;
  float iv = rsqrtf(var + 1e-5f);
  float r0 = (a0 - mean) * iv * g_an[t] + be_an[t];
  float r1 = (a1 - mean) * iv * g_an[256 + t] + be_an[256 + t];
  float t0 = bf2f(x1e[(size_t)row * DD + t]) + r0;
  float t1 = x2[(size_t)row * DD + t] + r1;
  tx[(size_t)row * DD2 + t] = f2bf(t0);
  tx[(size_t)row * DD2 + 256 + t] = f2bf(t1);
  __syncthreads();
  s = t0 + t1; q = t0 * t0 + t1 * t1;
#pragma unroll
  for (int m = 1; m < 64; m <<= 1) {
    s += __shfl_xor(s, m, 64);
    q += __shfl_xor(q, m, 64);
  }
  if ((t & 63) == 0) { ws[t >> 6] = s; ws[4 + (t >> 6)] = q; }
  __syncthreads();
  s = ws[0] + ws[1] + ws[2] + ws[3];
  q = ws[4] + ws[5] + ws[6] + ws[7];
  mean = s * (1.0f / DD2);
  var = q * (1.0f / DD2) - mean * mean;
  iv = rsqrtf(var + 1e-5f);
  txln[(size_t)row * DD2 + t] = f2bf((t0 - mean) * iv * g_n2[t] + be_n2[t]);
  txln[(size_t)row * DD2 + 256 + t] = f2bf((t1 - mean) * iv * g_n2[256 + t] + be_n2[256 + t]);
}

// ------- c8a_col: z-column dw-conv3d + skip + LN + GELU (round-7 form) -------
// 1024 blocks x 1024 threads, ONE channel per thread. Phase 1: conv all 16 z,
// per-wave LN partials -> LDS. Barrier. Phase 2: wave w reduces z=w. Barrier.
// Phase 3: LN+GELU+store all z. Practical floor for this fused design (~74us;
// 4 variants measured 72-118us — serial chain + all-channel LN is structural).
__global__ __launch_bounds__(1024) void c8a_col(
    const u16* __restrict__ h, const float* __restrict__ w_dwt,
    const float* __restrict__ b_dw, const float* __restrict__ g,
    const float* __restrict__ be, u16* __restrict__ ax) {
  const int bid = blockIdx.x;
  const int cidx = (bid & 7) * 128 + (bid >> 3);  // XCD-chunked, bijective
  const int b = cidx >> 8, y = (cidx >> 4) & 15, x = cidx & 15;
  const int t = threadIdx.x;  // channel
  const int lane = t & 63, wave = t >> 6;  // 16 waves
  const size_t hb = (size_t)b * NN * CC2;

  __shared__ float2 red[16][16];
  __shared__ float2 stats[16];

  int coln[9];
  float cmask[9];
#pragma unroll
  for (int dy = -1; dy <= 1; ++dy)
#pragma unroll
    for (int dx = -1; dx <= 1; ++dx) {
      int qq = (dy + 1) * 3 + (dx + 1);
      int yy = y + dy, xx = x + dx;
      bool ok = ((unsigned)yy < 16u) && ((unsigned)xx < 16u);
      coln[qq] = ((ok ? yy : y) << 4) | (ok ? xx : x);
      cmask[qq] = ok ? 1.f : 0.f;
    }

  float wr[3][9];
#pragma unroll
  for (int p = 0; p < 3; ++p)
#pragma unroll
    for (int qq = 0; qq < 9; ++qq)
      wr[p][qq] = w_dwt[(p * 9 + qq) * CC2 + t] * cmask[qq];
  const float bias = b_dw[t];

  u16 win[3][9];
#define LOADPLANE(ZL, SLOT)                                                   \
  do {                                                                        \
    if ((ZL) >= 0 && (ZL) < 16) {                                             \
      _Pragma("unroll") for (int qq = 0; qq < 9; ++qq) win[SLOT][qq] =        \
          h[hb + (size_t)((((ZL) << 8) | coln[qq])) * CC2 + t];               \
    } else {                                                                  \
      _Pragma("unroll") for (int qq = 0; qq < 9; ++qq) win[SLOT][qq] = 0;     \
    }                                                                         \
  } while (0)

  LOADPLANE(-1, 0);
  LOADPLANE(0, 1);
  LOADPLANE(1, 2);

  float vs[16];
#pragma unroll
  for (int z = 0; z < 16; ++z) {
    const int pm1 = z % 3, pz = (z + 1) % 3, pp1 = (z + 2) % 3;
    float a0 = bias;
#pragma unroll
    for (int qq = 0; qq < 9; ++qq) {
      a0 += bf2f(win[pm1][qq]) * wr[0][qq];
      a0 += bf2f(win[pz][qq]) * wr[1][qq];
      a0 += bf2f(win[pp1][qq]) * wr[2][qq];
    }
    float v = a0 + bf2f(win[pz][4]);  // skip-add (center)
    LOADPLANE(z + 2, pm1);            // prefetch; overwrite dead plane
    vs[z] = v;
    float s = v, q2 = v * v;
#pragma unroll
    for (int m = 1; m < 64; m <<= 1) {
      s += __shfl_xor(s, m, 64);
      q2 += __shfl_xor(q2, m, 64);
    }
    if (lane == 0) red[z][wave] = make_float2(s, q2);
  }
#undef LOADPLANE
  __syncthreads();

  {
    const int z = wave;
    float S = (lane < 16) ? red[z][lane].x : 0.f;
    float Q = (lane < 16) ? red[z][lane].y : 0.f;
#pragma unroll
    for (int m = 1; m < 16; m <<= 1) {
      S += __shfl_xor(S, m, 64);
      Q += __shfl_xor(Q, m, 64);
    }
    if (lane == 0) {
      float mean = S * (1.0f / CC2);
      float var = Q * (1.0f / CC2) - mean * mean;
      stats[z] = make_float2(mean, rsqrtf(var + 1e-5f));
    }
  }
  __syncthreads();

  const float gg = g[t], bb = be[t];
#pragma unroll
  for (int z = 0; z < 16; ++z) {
    float2 st = stats[z];
    float u = (vs[z] - st.x) * st.y * gg + bb;
    float s2 = 1.5957691216f * (u + 0.044715f * u * u * u);
    float o = u / (1.0f + __expf(-s2));
    ax[((size_t)(b * NN + ((z << 8) | (y << 4) | x))) * CC2 + t] = f2bf(o);
  }
}

extern "C" void kernel_launch(void* const* d_in, const int* in_sizes, int n_in,
                              void* d_out, int out_size, void* d_ws, size_t ws_size,
                              hipStream_t stream) {
  const float* x1    = (const float*)d_in[0];
  const float* x2    = (const float*)d_in[1];
  const float* w_x1  = (const float*)d_in[2];
  const float* b_x1  = (const float*)d_in[3];
  const float* g_n1  = (const float*)d_in[4];
  const float* be_n1 = (const float*)d_in[5];
  const float* w_rep = (const float*)d_in[6];
  const float* b_rep = (const float*)d_in[7];
  const float* g_an  = (const float*)d_in[8];
  const float* be_an = (const float*)d_in[9];
  const float* g_n2  = (const float*)d_in[10];
  const float* be_n2 = (const float*)d_in[11];
  const float* w_fc1 = (const float*)d_in[12];
  const float* b_fc1 = (const float*)d_in[13];
  const float* w_dw  = (const float*)d_in[14];
  const float* b_dw  = (const float*)d_in[15];
  const float* g_m1  = (const float*)d_in[16];
  const float* be_m1 = (const float*)d_in[17];
  const float* w_fc2 = (const float*)d_in[18];
  const float* b_fc2 = (const float*)d_in[19];
  const float* w_cat = (const float*)d_in[20];
  const float* b_cat = (const float*)d_in[21];
  const float* w_exp = (const float*)d_in[22];
  const float* g_up  = (const float*)d_in[23];
  const float* be_up = (const float*)d_in[24];

  char* ws = (char*)d_ws;
  float* out = (float*)d_out;

  u16*   x1e_b   = (u16*)(ws + 8 * MB);     // bf16 x1e; then mx
  u16*   n1T     = (u16*)(ws + 24 * MB);
  u16*   n2b     = (u16*)(ws + 32 * MB);
  u16*   n2T     = (u16*)(ws + 40 * MB);
  float* ctx     = (float*)(ws + 48 * MB);
  u16*   rep_b   = (u16*)(ws + 49 * MB);    // bf16 rep; then ax
  u16*   tx      = (u16*)(ws + 81 * MB);
  u16*   txln    = (u16*)(ws + 97 * MB);
  u16*   hbuf    = (u16*)(ws + 113 * MB);
  u16*   attT    = (u16*)(ws + 0);
  u16*   ax      = (u16*)(ws + 49 * MB);
  u16*   mx      = (u16*)(ws + 8 * MB);
  u16*   ybuf    = (u16*)(ws + 0);
  u16*   w_x1t   = (u16*)(ws + 145 * MB);
  u16*   w_rept  = w_x1t + 256 * 256;
  u16*   w_fc1t  = w_rept + 512 * 256;
  u16*   w_fc2t  = w_fc1t + 1024 * 512;
  u16*   w_catt  = w_fc2t + 512 * 1024;
  u16*   w_expt  = w_catt + 256 * 512;
  float* w_dwt   = (float*)(ws + 149 * MB);

  wprep_all<<<(1666048 + 255) / 256, 256, 0, stream>>>(
      w_x1, w_rep, w_fc1, w_fc2, w_cat, w_exp, w_dw,
      w_x1t, w_rept, w_fc1t, w_fc2t, w_catt, w_expt, w_dwt);

  gemm_mfma<256, 1, true><<<(ROWS / 128) * 2, 256, 0, stream>>>(
      (const u16*)x1, w_x1t, b_x1, nullptr, x1e_b, 2, nullptr, nullptr);
  ln256_both<<<2 * ROWS, 256, 0, stream>>>(x1e_b, x2, g_n1, be_n1, n1T, n2b, n2T);
  k34_ctx<<<BB * 256, 256, 0, stream>>>(n2T, n1T, ctx);
  k5_attT<<<ROWS, 256, 0, stream>>>(n2b, ctx, attT);
  gemm_mfma<256, 1><<<(ROWS / 128) * 4, 256, 0, stream>>>(
      attT, w_rept, b_rep, nullptr, rep_b, 4, nullptr, nullptr);
  l3_reptx<<<ROWS, 256, 0, stream>>>(rep_b, x1e_b, x2, g_an, be_an, g_n2, be_n2, tx, txln);
  gemm_mfma<512, 1><<<(ROWS / 128) * 8, 256, 0, stream>>>(
      txln, w_fc1t, b_fc1, nullptr, hbuf, 8, nullptr, nullptr);
  c8a_col<<<1024, 1024, 0, stream>>>(hbuf, w_dwt, b_dw, g_m1, be_m1, ax);
  gemm_mfma<1024, 2><<<(ROWS / 128) * 4, 256, 0, stream>>>(
      ax, w_fc2t, b_fc2, tx, mx, 4, nullptr, nullptr);
  gemm_mfma<512, 1><<<(ROWS / 128) * 2, 256, 0, stream>>>(
      mx, w_catt, b_cat, nullptr, ybuf, 2, nullptr, nullptr);
  gemm_mfma<256, 3><<<(ROWS / 128) * 8, 256, 0, stream>>>(
      ybuf, w_expt, nullptr, nullptr, out, 8, g_up, be_up);
}